// Round 6
// baseline (7292.464 us; speedup 1.0000x reference)
//
#include <hip/hip_runtime.h>
#include <cstdint>
#include <cstddef>

// Autoregressive 3-layer LSTM, B=512, T=75, IN=96, H=1024, bf16 MFMA compute.
// R6: persistent kernel, cached A-reads, ONE L2 inv per step.
//   R5 post-mortem: FETCH=43MB/step in R4 AND R5 -> W eviction is CAPACITY
//   (5.4MB/XCD > 4MB L2), not the inv. R5's L2-bypassed A-reads added ~172MB/step
//   of un-deduped MALL traffic (32 panel-blocks x same A-tile) -> latency
//   inflation + straggler spread at every sync. Fix:
//   - A-staging + FC h2 reads: normal cached loads (L2 dedupes 4 co-XCD readers).
//   - Correctness: ONE seq_cst agent fence (wbl2+inv) per step, at the FC sync.
//     Stale-copy analysis: any same-parity cached activation copy is >= 1 step
//     old and has a per-step inv between its caching and its next read.
//     Cross-block writes stay write-through atomics (no stale copies created);
//     'out' dirty lines flushed by the per-step release.
//   - Other 3 syncs: R5's fence-free single-hop counter barrier (proven).
// GEMM stage: depth-3 prefetch, 4-buf LDS ring, counted vmcnt, XOR-swizzled LDS,
// gate-grouped 64x128 tile, fused cell epilogue; c-state in registers.

typedef unsigned short u16;
typedef float v4f __attribute__((ext_vector_type(4)));
typedef short v8s __attribute__((ext_vector_type(8)));    // 8 bf16 (4 VGPRs)
typedef u16   v8u16 __attribute__((ext_vector_type(8)));

#define BATCH 512
#define H_DIM 1024
#define GATES 4096
#define T_STEPS 75
#define IN_DIM 96
#define K0P 1152              // layer0 K padded: 96 + 1024 + 32 zeros
#define K12 2048              // layers 1,2 K: 1024 + 1024
#define NBLK 256

__device__ __forceinline__ float bf2f(u16 u) {
    unsigned int x = ((unsigned int)u) << 16;
    return __builtin_bit_cast(float, x);
}
__device__ __forceinline__ u16 f2bf(float f) {   // round-to-nearest-even
    unsigned int x = __builtin_bit_cast(unsigned int, f);
    x += 0x7fffu + ((x >> 16) & 1u);
    return (u16)(x >> 16);
}
// cached global->LDS (weights AND activations; L2 dedupes co-XCD readers)
__device__ __forceinline__ void gload16(const void* g, void* l) {
    __builtin_amdgcn_global_load_lds(
        (const __attribute__((address_space(1))) void*)g,
        (__attribute__((address_space(3))) void*)l, 16, 0, 0);
}
__device__ __forceinline__ void st_agent_u32(unsigned int* p, unsigned int v) {
    __hip_atomic_store(p, v, __ATOMIC_RELAXED, __HIP_MEMORY_SCOPE_AGENT);
}

// ---- grid barrier: single-hop counter + done flag ----
// bar2[2g] = arrive counter, bar2[2g+1] = done flag (zero-initialized).
// do_fence=true (once per step, FC sync): release (wbl2: flush 'out' dirty
// lines) before arrive; acquire (inv L1/L2: kill stale activation copies)
// after the wait. Other syncs: fence-free (write-through data + vmcnt drain
// in the entry __syncthreads).
__device__ __forceinline__ void grid_sync(int* bar2, int g, bool do_fence) {
    __syncthreads();   // all waves: s_waitcnt vmcnt(0) -> stores visible
    if (threadIdx.x == 0) {
        if (do_fence)
            __builtin_amdgcn_fence(__ATOMIC_RELEASE, "agent");   // wbl2
        int old = __hip_atomic_fetch_add(&bar2[2 * g], 1,
                                         __ATOMIC_RELAXED, __HIP_MEMORY_SCOPE_AGENT);
        if (old == NBLK - 1) {
            __hip_atomic_store(&bar2[2 * g + 1], 1,
                               __ATOMIC_RELAXED, __HIP_MEMORY_SCOPE_AGENT);
        } else {
            int spins = 0;
            while (!__hip_atomic_load(&bar2[2 * g + 1],
                                      __ATOMIC_RELAXED, __HIP_MEMORY_SCOPE_AGENT)) {
                if (++spins > (1 << 17)) break;   // watchdog: fail fast, not hang
                __builtin_amdgcn_s_sleep(1);
            }
        }
        if (do_fence)
            __builtin_amdgcn_fence(__ATOMIC_ACQUIRE, "agent");   // inv
    }
    __syncthreads();
}

// ---- fused gates-GEMM + LSTM cell stage (block tile 64 rows x 4gates*32j) ----
__device__ __forceinline__ void gemm_stage(
    char* smem, const u16* __restrict__ A, const u16* __restrict__ W,
    int K, int nk, v4f bv, v4f& cA, v4f& cB,
    u16* __restrict__ h1, int h1s, u16* __restrict__ h2, int h2s,
    int bm, int j0)
{
    u16* sA = (u16*)smem;              // 4 bufs x 4096 u16 (64x64, 8KB each)
    u16* sB = (u16*)(smem + 32768);    // 4 bufs x 8192 u16 (128x64, 16KB each)

    const int tid  = threadIdx.x;
    const int lane = tid & 63;
    const int wid  = tid >> 6;
    const int wm   = (wid >> 1) * 32;
    const int wn   = (wid & 1) * 64;
    const int l15  = lane & 15;
    const int lq   = lane >> 4;

    v4f acc[2][4];
    #pragma unroll
    for (int nf = 0; nf < 4; ++nf) {
        v4f tv = {bv[nf], bv[nf], bv[nf], bv[nf]};
        acc[0][nf] = tv; acc[1][nf] = tv;
    }

    const int srow = tid >> 3;                                   // 0..31
    const int kcs  = ((tid & 7) ^ (srow & 7)) << 3;              // swizzled src k-elem

    auto stage = [&](int b, int k0) {
        u16* sa = sA + b * 4096;
        u16* sb = sB + b * 8192;
        gload16(A + (size_t)(bm + srow) * K + k0 + kcs,      sa + tid * 8);
        gload16(A + (size_t)(bm + 32 + srow) * K + k0 + kcs, sa + 2048 + tid * 8);
        #pragma unroll
        for (int q = 0; q < 4; ++q)   // W rows: gate q, j0 + srow
            gload16(W + (size_t)(q * H_DIM + j0 + srow) * K + k0 + kcs,
                    sb + q * 2048 + tid * 8);
    };

    // depth-3 prologue
    {
        const int npre = nk < 3 ? nk : 3;
        for (int p = 0; p < npre; ++p) stage(p, p * 64);
    }

    #pragma unroll 1
    for (int tt = 0; tt < nk; ++tt) {
        const int cur = tt & 3;
        if (tt + 3 < nk) stage((tt + 3) & 3, (tt + 3) * 64);
        const int ahead = (nk - 1 - tt) < 3 ? (nk - 1 - tt) : 3;
        if (ahead == 3)      asm volatile("s_waitcnt vmcnt(18)" ::: "memory");
        else if (ahead == 2) asm volatile("s_waitcnt vmcnt(12)" ::: "memory");
        else if (ahead == 1) asm volatile("s_waitcnt vmcnt(6)"  ::: "memory");
        else                 asm volatile("s_waitcnt vmcnt(0)"  ::: "memory");
        asm volatile("s_barrier" ::: "memory");

        const char* sa = (const char*)(sA + cur * 4096);
        const char* sb = (const char*)(sB + cur * 8192);
        v8s af[2][2], bfr[4][2];
        #pragma unroll
        for (int mf = 0; mf < 2; ++mf)
            #pragma unroll
            for (int ks = 0; ks < 2; ++ks) {
                const int row = wm + mf * 16 + l15;
                const int ch  = ks * 4 + lq;
                af[mf][ks] = *(const v8s*)(sa + row * 128 + (((ch ^ (row & 7))) << 4));
            }
        #pragma unroll
        for (int nf = 0; nf < 4; ++nf)
            #pragma unroll
            for (int ks = 0; ks < 2; ++ks) {
                const int row = wn + nf * 16 + l15;
                const int ch  = ks * 4 + lq;
                bfr[nf][ks] = *(const v8s*)(sb + row * 128 + (((ch ^ (row & 7))) << 4));
            }
        #pragma unroll
        for (int ks = 0; ks < 2; ++ks)
            #pragma unroll
            for (int mf = 0; mf < 2; ++mf)
                #pragma unroll
                for (int nf = 0; nf < 4; ++nf)
                    acc[mf][nf] = __builtin_amdgcn_mfma_f32_16x16x32_bf16(
                        af[mf][ks], bfr[nf][ks], acc[mf][nf], 0, 0, 0);
        asm volatile("s_barrier" ::: "memory");
    }

    // ---- epilogue: gates -> LDS, then cell (c in registers) ----
    float* sG = (float*)smem;   // [64][132] f32 = 33792B (reuses staging LDS)
    #pragma unroll
    for (int mf = 0; mf < 2; ++mf)
        #pragma unroll
        for (int nf = 0; nf < 4; ++nf)
            #pragma unroll
            for (int r = 0; r < 4; ++r)
                sG[(wm + mf * 16 + lq * 4 + r) * 132 + wn + nf * 16 + l15] =
                    acc[mf][nf][r];
    __syncthreads();

    const int erow = tid >> 2;           // 0..63
    const int jj   = (tid & 3) * 8;      // 0,8,16,24
    const int gb   = bm + erow;
    const float* sGr = sG + erow * 132;
    v4f n0, n1;
    v8u16 hv;
    #pragma unroll
    for (int q = 0; q < 8; ++q) {
        const float gi = sGr[      jj + q];
        const float gf = sGr[32  + jj + q];
        const float gg = sGr[64  + jj + q];
        const float go = sGr[96  + jj + q];
        const float cv = (q < 4) ? cA[q] : cB[q - 4];
        const float ii = 1.f / (1.f + __expf(-gi));
        const float ff = 1.f / (1.f + __expf(-gf));
        const float g2 = tanhf(gg);
        const float oo = 1.f / (1.f + __expf(-go));
        const float cq = ff * cv + ii * g2;
        if (q < 4) n0[q] = cq; else n1[q - 4] = cq;
        hv[q] = f2bf(oo * tanhf(cq));
    }
    cA = n0; cB = n1;
    // h writes: agent-scope atomic u32 stores (write-through; no stale copies)
    unsigned int* d1 = (unsigned int*)(h1 + (size_t)gb * h1s + j0 + jj);
    #pragma unroll
    for (int w2 = 0; w2 < 4; ++w2) {
        unsigned int val = (unsigned int)hv[2 * w2] | ((unsigned int)hv[2 * w2 + 1] << 16);
        st_agent_u32(d1 + w2, val);
    }
    if (h2) {
        unsigned int* d2 = (unsigned int*)(h2 + (size_t)gb * h2s + j0 + jj);
        #pragma unroll
        for (int w2 = 0; w2 < 4; ++w2) {
            unsigned int val = (unsigned int)hv[2 * w2] | ((unsigned int)hv[2 * w2 + 1] << 16);
            st_agent_u32(d2 + w2, val);
        }
    }
}

// ---- FC 1024->96 + hardtanh; 2 batch rows per block ----
__device__ __forceinline__ void fc_stage(
    char* smem, const u16* __restrict__ h2, int h2s,
    const u16* __restrict__ w, const float* __restrict__ fcb,
    float* __restrict__ out, u16* __restrict__ xdst, int t, int id)
{
    float* sh = (float*)smem;            // [2][1024] f32
    const int tid  = threadIdx.x;
    const int half = tid >> 7;           // 0,1
    const int htid = tid & 127;
    const int b    = id * 2 + half;      // 0..511
    // cached read: stale copies impossible (per-step inv between prior
    // same-parity read and this one; writes are write-through)
    v8u16 hvv = *(const v8u16*)(h2 + (size_t)b * h2s + htid * 8);
    #pragma unroll
    for (int q = 0; q < 8; ++q) sh[half * H_DIM + htid * 8 + q] = bf2f(hvv[q]);
    __syncthreads();
    if (htid < IN_DIM) {
        const u16* wr = w + (size_t)htid * H_DIM;
        const float* shr = sh + half * H_DIM;
        float acc = fcb[htid];
        #pragma unroll 4
        for (int k = 0; k < H_DIM; k += 8) {
            v8u16 wv = *(const v8u16*)(wr + k);
            #pragma unroll
            for (int q = 0; q < 8; ++q) acc += shr[k + q] * bf2f(wv[q]);
        }
        acc = fminf(1.f, fmaxf(-1.f, acc));
        out[(size_t)b * (T_STEPS * IN_DIM) + t * IN_DIM + htid] = acc;
        // x write crosses the next sync: pair lanes -> one atomic u32 store
        float o2 = __shfl_xor(acc, 1);
        if ((htid & 1) == 0) {
            unsigned int val = (unsigned int)f2bf(acc) | ((unsigned int)f2bf(o2) << 16);
            st_agent_u32((unsigned int*)(xdst + (size_t)b * K0P + htid), val);
        }
    }
}

// ================= the persistent kernel =================
__global__ __launch_bounds__(256, 1) void lstm_all_k(
    const u16* __restrict__ w0, const u16* __restrict__ w1, const u16* __restrict__ w2,
    u16* A00, u16* A01, u16* A10, u16* A11, u16* A20, u16* A21,
    const u16* __restrict__ fcw, const float* __restrict__ bsum,
    const float* __restrict__ cells, const float* __restrict__ fcb,
    float* __restrict__ out, int* bar2)
{
    __shared__ __align__(16) char smem[98304];

    const int tid  = threadIdx.x;
    const int lane = tid & 63;
    const int wid  = tid >> 6;
    const int wn   = (wid & 1) * 64;
    const int l15  = lane & 15;

    // XCD swizzle: 8 m-blocks sharing a W-panel land on one XCD
    const int id    = blockIdx.x;
    const int panel = (id & 7) * 4 + (id >> 6);   // 0..31  (j-panel)
    const int mblk  = (id >> 3) & 7;              // 0..7
    const int bm    = mblk * 64;
    const int j0    = panel * 32;

    // per-layer bias (this thread's 4 nf columns)
    v4f bv0, bv1, bv2;
    #pragma unroll
    for (int nf = 0; nf < 4; ++nf) {
        const int ncol = wn + nf * 16 + l15;
        const int idx  = (ncol >> 5) * H_DIM + j0 + (ncol & 31);
        bv0[nf] = bsum[idx];
        bv1[nf] = bsum[GATES + idx];
        bv2[nf] = bsum[2 * GATES + idx];
    }

    // persistent c-state in registers: this thread owns c[layer][gb][j0+jj..+7]
    const int erow = tid >> 2;
    const int jj   = (tid & 3) * 8;
    const int gb   = bm + erow;
    v4f c0a, c0b, c1a, c1b, c2a, c2b;
    {
        const float* cr = cells + (size_t)gb * H_DIM + j0 + jj;
        c0a = *(const v4f*)cr; c0b = *(const v4f*)(cr + 4);
        cr += (size_t)BATCH * H_DIM;
        c1a = *(const v4f*)cr; c1b = *(const v4f*)(cr + 4);
        cr += (size_t)BATCH * H_DIM;
        c2a = *(const v4f*)cr; c2b = *(const v4f*)(cr + 4);
    }

    int g = 0;
    #pragma unroll 1
    for (int t = 0; t < T_STEPS; ++t) {
        const int pr = t & 1;
        u16* A0r = pr ? A01 : A00;  u16* A0w = pr ? A00 : A01;
        u16* A1r = pr ? A11 : A10;  u16* A1w = pr ? A10 : A11;
        u16* A2r = pr ? A21 : A20;  u16* A2w = pr ? A20 : A21;

        // layer 0: reads [x(t)|h0(t-1)]; h0 -> own next-parity slot + layer1 x
        gemm_stage(smem, A0r, w0, K0P, K0P / 64, bv0, c0a, c0b,
                   A0w + IN_DIM, K0P, A1r, K12, bm, j0);
        grid_sync(bar2, ++g, false);
        // layer 1
        gemm_stage(smem, A1r, w1, K12, K12 / 64, bv1, c1a, c1b,
                   A1w + H_DIM, K12, A2r, K12, bm, j0);
        grid_sync(bar2, ++g, false);
        // layer 2
        gemm_stage(smem, A2r, w2, K12, K12 / 64, bv2, c2a, c2b,
                   A2w + H_DIM, K12, (u16*)nullptr, 0, bm, j0);
        grid_sync(bar2, ++g, false);
        // FC: reads h2(t) (parity pn), writes out[:,t,:] and x(t+1)
        fc_stage(smem, A2w + H_DIM, K12, fcw, fcb, out, A0w, t, id);
        grid_sync(bar2, ++g, true);   // per-step wbl2 + inv lives here
    }
}

// ================= prologue =================
__global__ __launch_bounds__(256) void convpack_k(
    const float* __restrict__ src, int srcStride,
    u16* __restrict__ dst, int dstStride, int cols8, long total8)
{
    long i = (long)blockIdx.x * 256 + threadIdx.x;
    if (i >= total8) return;
    const int r  = (int)(i / cols8);
    const int cc = (int)(i - (long)r * cols8) * 8;
    const float* s = src + (size_t)r * srcStride + cc;
    v4f a = *(const v4f*)s;
    v4f b = *(const v4f*)(s + 4);
    v8u16 o;
    #pragma unroll
    for (int q = 0; q < 4; ++q) { o[q] = f2bf(a[q]); o[4 + q] = f2bf(b[q]); }
    *(v8u16*)(dst + (size_t)r * dstStride + cc) = o;
}

__global__ __launch_bounds__(256) void zero16_k(
    u16* __restrict__ dst, int dstStride, int cols8, long total8)
{
    long i = (long)blockIdx.x * 256 + threadIdx.x;
    if (i >= total8) return;
    const int r  = (int)(i / cols8);
    const int cc = (int)(i - (long)r * cols8) * 8;
    v8u16 z = {0, 0, 0, 0, 0, 0, 0, 0};
    *(v8u16*)(dst + (size_t)r * dstStride + cc) = z;
}

__global__ __launch_bounds__(256) void add_k(
    const float* __restrict__ a, const float* __restrict__ b,
    float* __restrict__ o, int n)
{
    int i = blockIdx.x * 256 + threadIdx.x;
    if (i < n) o[i] = a[i] + b[i];
}

extern "C" void kernel_launch(void* const* d_in, const int* in_sizes, int n_in,
                              void* d_out, int out_size, void* d_ws, size_t ws_size,
                              hipStream_t stream)
{
    const float* inputs  = (const float*)d_in[0];
    const float* hiddens = (const float*)d_in[1];
    const float* cells   = (const float*)d_in[2];
    const float* Wih[3]  = {(const float*)d_in[3], (const float*)d_in[7],  (const float*)d_in[11]};
    const float* Whh[3]  = {(const float*)d_in[4], (const float*)d_in[8],  (const float*)d_in[12]};
    const float* bih[3]  = {(const float*)d_in[5], (const float*)d_in[9],  (const float*)d_in[13]};
    const float* bhh[3]  = {(const float*)d_in[6], (const float*)d_in[10], (const float*)d_in[14]};
    const float* fc_w    = (const float*)d_in[15];
    const float* fc_b    = (const float*)d_in[16];
    float* out = (float*)d_out;

    // ---- workspace carve-up ----
    char* p = (char*)d_ws;
    auto take = [&](size_t bytes) -> void* {
        void* r = p; p += (bytes + 255) & ~(size_t)255; return r;
    };
    const int Kl[3]  = {K0P, K12, K12};
    const int Kin[3] = {IN_DIM, H_DIM, H_DIM};
    u16* wcat[3];
    for (int l = 0; l < 3; ++l) wcat[l] = (u16*)take((size_t)GATES * Kl[l] * 2);
    u16* Ab[3][2];
    for (int l = 0; l < 3; ++l)
        for (int q = 0; q < 2; ++q) Ab[l][q] = (u16*)take((size_t)BATCH * Kl[l] * 2);
    u16*   fcwb = (u16*)take((size_t)IN_DIM * H_DIM * 2);
    float* bsum = (float*)take((size_t)3 * GATES * 4);
    int*   bar  = (int*)take(4096);
    if ((size_t)(p - (char*)d_ws) > ws_size) return;

    auto pack = [&](const float* s, int ss, u16* d, int ds, int rows, int cols) {
        long t8 = (long)rows * (cols / 8);
        convpack_k<<<(int)((t8 + 255) / 256), 256, 0, stream>>>(s, ss, d, ds, cols / 8, t8);
    };
    auto zero = [&](u16* d, int ds, int rows, int cols) {
        long t8 = (long)rows * (cols / 8);
        zero16_k<<<(int)((t8 + 255) / 256), 256, 0, stream>>>(d, ds, cols / 8, t8);
    };

    // weights -> bf16 concatenated [Wih | Whh | pad]
    for (int l = 0; l < 3; ++l) {
        pack(Wih[l], Kin[l], wcat[l],           Kl[l], GATES, Kin[l]);
        pack(Whh[l], H_DIM,  wcat[l] + Kin[l],  Kl[l], GATES, H_DIM);
    }
    zero(wcat[0] + IN_DIM + H_DIM, K0P, GATES, K0P - IN_DIM - H_DIM);
    pack(fc_w, H_DIM, fcwb, H_DIM, IN_DIM, H_DIM);

    // initial states (parity 0), x0, pads (both parities of layer0)
    for (int l = 0; l < 3; ++l)
        pack(hiddens + (size_t)l * BATCH * H_DIM, H_DIM,
             Ab[l][0] + Kin[l], Kl[l], BATCH, H_DIM);
    pack(inputs, T_STEPS * IN_DIM, Ab[0][0], K0P, BATCH, IN_DIM);   // x_0
    zero(Ab[0][0] + IN_DIM + H_DIM, K0P, BATCH, K0P - IN_DIM - H_DIM);
    zero(Ab[0][1] + IN_DIM + H_DIM, K0P, BATCH, K0P - IN_DIM - H_DIM);

    for (int l = 0; l < 3; ++l)
        add_k<<<16, 256, 0, stream>>>(bih[l], bhh[l], bsum + l * GATES, GATES);
    hipMemsetAsync(bar, 0, 4096, stream);

    // ---- the whole recurrence: one persistent kernel, plain launch ----
    lstm_all_k<<<NBLK, 256, 0, stream>>>(
        wcat[0], wcat[1], wcat[2],
        Ab[0][0], Ab[0][1], Ab[1][0], Ab[1][1], Ab[2][0], Ab[2][1],
        fcwb, bsum, cells, fc_b, out,
        bar);
}

// Round 7
// 5779.861 us; speedup vs baseline: 1.2617x; 1.2617x over previous
//
#include <hip/hip_runtime.h>
#include <cstdint>
#include <cstddef>

// Autoregressive 3-layer LSTM, B=512, T=75, IN=96, H=1024, bf16 MFMA compute.
// R7: R5 memory scheme (fence-free, bypass-A, write-through h/x) + TWO-LEVEL
// CONTENTION-SEPARATED grid barrier.
//   R6 post-mortem: barriers ~16us each (4/step = ~60us of the 90us step).
//   Root cause: arrive counter and done flag shared ONE cacheline -> 256
//   serialized far RMWs fighting a 255-block poll flood on the same line.
//   Fix: 8 group-counter lines (32 RMWs each, never polled) -> root line
//   (8 RMWs, never polled by spinners) -> done flag on its OWN line (poll-only).
//   Monotone generation counters, no reset, race-safe by exact-equality check.
// GEMM stage: depth-3 prefetch, 4-buf LDS ring, counted vmcnt, XOR-swizzled LDS,
// gate-grouped 64x128 tile, fused cell epilogue; c-state in registers.

typedef unsigned short u16;
typedef float v4f __attribute__((ext_vector_type(4)));
typedef short v8s __attribute__((ext_vector_type(8)));    // 8 bf16 (4 VGPRs)
typedef u16   v8u16 __attribute__((ext_vector_type(8)));

#define BATCH 512
#define H_DIM 1024
#define GATES 4096
#define T_STEPS 75
#define IN_DIM 96
#define K0P 1152              // layer0 K padded: 96 + 1024 + 32 zeros
#define K12 2048              // layers 1,2 K: 1024 + 1024
#define NBLK 256

__device__ __forceinline__ float bf2f(u16 u) {
    unsigned int x = ((unsigned int)u) << 16;
    return __builtin_bit_cast(float, x);
}
__device__ __forceinline__ u16 f2bf(float f) {   // round-to-nearest-even
    unsigned int x = __builtin_bit_cast(unsigned int, f);
    x += 0x7fffu + ((x >> 16) & 1u);
    return (u16)(x >> 16);
}
// cached load (weights: read-only; streamed from L2/L3)
__device__ __forceinline__ void gload16(const void* g, void* l) {
    __builtin_amdgcn_global_load_lds(
        (const __attribute__((address_space(1))) void*)g,
        (__attribute__((address_space(3))) void*)l, 16, 0, 0);
}
// coherent load (activations written by other blocks since last sync):
// aux = sc0|sc1 = 0x11 -> bypass stale L1/L2, read from coherence point
__device__ __forceinline__ void gload16c(const void* g, void* l) {
    __builtin_amdgcn_global_load_lds(
        (const __attribute__((address_space(1))) void*)g,
        (__attribute__((address_space(3))) void*)l, 16, 0, 0x11);
}
__device__ __forceinline__ void st_agent_u32(unsigned int* p, unsigned int v) {
    __hip_atomic_store(p, v, __ATOMIC_RELAXED, __HIP_MEMORY_SCOPE_AGENT);
}
__device__ __forceinline__ unsigned int ld_agent_u32(const unsigned int* p) {
    return __hip_atomic_load(p, __ATOMIC_RELAXED, __HIP_MEMORY_SCOPE_AGENT);
}

// ---- two-level grid barrier, contention-separated ----
// bar[x*32]  x=0..7 : group arrive counters (one 128B line each; NEVER polled)
// bar[256]           : root counter (line 8; touched by 8 blocks only)
// bar[288]           : done generation (line 9; POLL-ONLY, single writer/gen)
// Monotone counters: gen g complete when grp==32g, root==8g. Exactly one
// completer per level per gen (old+1 equality), race-safe across generations.
// Fence-free: cross-block data is write-through (visible once vmcnt drains in
// the entry __syncthreads) and read L2-bypassing after the barrier.
__device__ __forceinline__ void grid_sync(int* bar, int g) {
    __syncthreads();   // all waves: s_waitcnt vmcnt(0) -> stores visible
    if (threadIdx.x == 0) {
        int old = __hip_atomic_fetch_add(&bar[(blockIdx.x & 7) * 32], 1,
                                         __ATOMIC_RELAXED, __HIP_MEMORY_SCOPE_AGENT);
        if (old + 1 == 32 * g) {            // this block completed its group
            int r = __hip_atomic_fetch_add(&bar[256], 1,
                                           __ATOMIC_RELAXED, __HIP_MEMORY_SCOPE_AGENT);
            if (r + 1 == 8 * g)             // all groups complete
                __hip_atomic_store(&bar[288], g,
                                   __ATOMIC_RELAXED, __HIP_MEMORY_SCOPE_AGENT);
        }
        int spins = 0;
        while (__hip_atomic_load(&bar[288],
                                 __ATOMIC_RELAXED, __HIP_MEMORY_SCOPE_AGENT) < g) {
            if (++spins > (1 << 17)) break;   // watchdog: fail fast, not hang
            __builtin_amdgcn_s_sleep(1);
        }
    }
    __syncthreads();
}

// ---- fused gates-GEMM + LSTM cell stage (block tile 64 rows x 4gates*32j) ----
__device__ __forceinline__ void gemm_stage(
    char* smem, const u16* __restrict__ A, const u16* __restrict__ W,
    int K, int nk, v4f bv, v4f& cA, v4f& cB,
    u16* __restrict__ h1, int h1s, u16* __restrict__ h2, int h2s,
    int bm, int j0)
{
    u16* sA = (u16*)smem;              // 4 bufs x 4096 u16 (64x64, 8KB each)
    u16* sB = (u16*)(smem + 32768);    // 4 bufs x 8192 u16 (128x64, 16KB each)

    const int tid  = threadIdx.x;
    const int lane = tid & 63;
    const int wid  = tid >> 6;
    const int wm   = (wid >> 1) * 32;
    const int wn   = (wid & 1) * 64;
    const int l15  = lane & 15;
    const int lq   = lane >> 4;

    v4f acc[2][4];
    #pragma unroll
    for (int nf = 0; nf < 4; ++nf) {
        v4f tv = {bv[nf], bv[nf], bv[nf], bv[nf]};
        acc[0][nf] = tv; acc[1][nf] = tv;
    }

    const int srow = tid >> 3;                                   // 0..31
    const int kcs  = ((tid & 7) ^ (srow & 7)) << 3;              // swizzled src k-elem

    auto stage = [&](int b, int k0) {
        u16* sa = sA + b * 4096;
        u16* sb = sB + b * 8192;
        // A: activations (cross-block producers) -> coherent
        gload16c(A + (size_t)(bm + srow) * K + k0 + kcs,      sa + tid * 8);
        gload16c(A + (size_t)(bm + 32 + srow) * K + k0 + kcs, sa + 2048 + tid * 8);
        // W: read-only weights -> cached
        #pragma unroll
        for (int q = 0; q < 4; ++q)   // W rows: gate q, j0 + srow
            gload16(W + (size_t)(q * H_DIM + j0 + srow) * K + k0 + kcs,
                    sb + q * 2048 + tid * 8);
    };

    // depth-3 prologue
    {
        const int npre = nk < 3 ? nk : 3;
        for (int p = 0; p < npre; ++p) stage(p, p * 64);
    }

    #pragma unroll 1
    for (int tt = 0; tt < nk; ++tt) {
        const int cur = tt & 3;
        if (tt + 3 < nk) stage((tt + 3) & 3, (tt + 3) * 64);
        const int ahead = (nk - 1 - tt) < 3 ? (nk - 1 - tt) : 3;
        if (ahead == 3)      asm volatile("s_waitcnt vmcnt(18)" ::: "memory");
        else if (ahead == 2) asm volatile("s_waitcnt vmcnt(12)" ::: "memory");
        else if (ahead == 1) asm volatile("s_waitcnt vmcnt(6)"  ::: "memory");
        else                 asm volatile("s_waitcnt vmcnt(0)"  ::: "memory");
        asm volatile("s_barrier" ::: "memory");

        const char* sa = (const char*)(sA + cur * 4096);
        const char* sb = (const char*)(sB + cur * 8192);
        v8s af[2][2], bfr[4][2];
        #pragma unroll
        for (int mf = 0; mf < 2; ++mf)
            #pragma unroll
            for (int ks = 0; ks < 2; ++ks) {
                const int row = wm + mf * 16 + l15;
                const int ch  = ks * 4 + lq;
                af[mf][ks] = *(const v8s*)(sa + row * 128 + (((ch ^ (row & 7))) << 4));
            }
        #pragma unroll
        for (int nf = 0; nf < 4; ++nf)
            #pragma unroll
            for (int ks = 0; ks < 2; ++ks) {
                const int row = wn + nf * 16 + l15;
                const int ch  = ks * 4 + lq;
                bfr[nf][ks] = *(const v8s*)(sb + row * 128 + (((ch ^ (row & 7))) << 4));
            }
        #pragma unroll
        for (int ks = 0; ks < 2; ++ks)
            #pragma unroll
            for (int mf = 0; mf < 2; ++mf)
                #pragma unroll
                for (int nf = 0; nf < 4; ++nf)
                    acc[mf][nf] = __builtin_amdgcn_mfma_f32_16x16x32_bf16(
                        af[mf][ks], bfr[nf][ks], acc[mf][nf], 0, 0, 0);
        asm volatile("s_barrier" ::: "memory");
    }

    // ---- epilogue: gates -> LDS, then cell (c in registers) ----
    float* sG = (float*)smem;   // [64][132] f32 = 33792B (reuses staging LDS)
    #pragma unroll
    for (int mf = 0; mf < 2; ++mf)
        #pragma unroll
        for (int nf = 0; nf < 4; ++nf)
            #pragma unroll
            for (int r = 0; r < 4; ++r)
                sG[(wm + mf * 16 + lq * 4 + r) * 132 + wn + nf * 16 + l15] =
                    acc[mf][nf][r];
    __syncthreads();

    const int erow = tid >> 2;           // 0..63
    const int jj   = (tid & 3) * 8;      // 0,8,16,24
    const int gb   = bm + erow;
    const float* sGr = sG + erow * 132;
    v4f n0, n1;
    v8u16 hv;
    #pragma unroll
    for (int q = 0; q < 8; ++q) {
        const float gi = sGr[      jj + q];
        const float gf = sGr[32  + jj + q];
        const float gg = sGr[64  + jj + q];
        const float go = sGr[96  + jj + q];
        const float cv = (q < 4) ? cA[q] : cB[q - 4];
        const float ii = 1.f / (1.f + __expf(-gi));
        const float ff = 1.f / (1.f + __expf(-gf));
        const float g2 = tanhf(gg);
        const float oo = 1.f / (1.f + __expf(-go));
        const float cq = ff * cv + ii * g2;
        if (q < 4) n0[q] = cq; else n1[q - 4] = cq;
        hv[q] = f2bf(oo * tanhf(cq));
    }
    cA = n0; cB = n1;
    // h writes: agent-scope atomic u32 stores (write-through; L2 never dirty)
    unsigned int* d1 = (unsigned int*)(h1 + (size_t)gb * h1s + j0 + jj);
    #pragma unroll
    for (int w2 = 0; w2 < 4; ++w2) {
        unsigned int val = (unsigned int)hv[2 * w2] | ((unsigned int)hv[2 * w2 + 1] << 16);
        st_agent_u32(d1 + w2, val);
    }
    if (h2) {
        unsigned int* d2 = (unsigned int*)(h2 + (size_t)gb * h2s + j0 + jj);
        #pragma unroll
        for (int w2 = 0; w2 < 4; ++w2) {
            unsigned int val = (unsigned int)hv[2 * w2] | ((unsigned int)hv[2 * w2 + 1] << 16);
            st_agent_u32(d2 + w2, val);
        }
    }
}

// ---- FC 1024->96 + hardtanh; 2 batch rows per block ----
__device__ __forceinline__ void fc_stage(
    char* smem, const u16* __restrict__ h2, int h2s,
    const u16* __restrict__ w, const float* __restrict__ fcb,
    float* __restrict__ out, u16* __restrict__ xdst, int t, int id)
{
    float* sh = (float*)smem;            // [2][1024] f32
    const int tid  = threadIdx.x;
    const int half = tid >> 7;           // 0,1
    const int htid = tid & 127;
    const int b    = id * 2 + half;      // 0..511
    // h2 was written cross-block since last sync -> coherent u32 loads
    const unsigned int* hp = (const unsigned int*)(h2 + (size_t)b * h2s + htid * 8);
    #pragma unroll
    for (int w4 = 0; w4 < 4; ++w4) {
        unsigned int u = ld_agent_u32(hp + w4);
        sh[half * H_DIM + htid * 8 + 2 * w4]     = bf2f((u16)(u & 0xffffu));
        sh[half * H_DIM + htid * 8 + 2 * w4 + 1] = bf2f((u16)(u >> 16));
    }
    __syncthreads();
    if (htid < IN_DIM) {
        const u16* wr = w + (size_t)htid * H_DIM;
        const float* shr = sh + half * H_DIM;
        float acc = fcb[htid];
        #pragma unroll 4
        for (int k = 0; k < H_DIM; k += 8) {
            v8u16 wv = *(const v8u16*)(wr + k);
            #pragma unroll
            for (int q = 0; q < 8; ++q) acc += shr[k + q] * bf2f(wv[q]);
        }
        acc = fminf(1.f, fmaxf(-1.f, acc));
        out[(size_t)b * (T_STEPS * IN_DIM) + t * IN_DIM + htid] = acc;
        // x write crosses the next sync: pair lanes -> one atomic u32 store
        float o2 = __shfl_xor(acc, 1);
        if ((htid & 1) == 0) {
            unsigned int val = (unsigned int)f2bf(acc) | ((unsigned int)f2bf(o2) << 16);
            st_agent_u32((unsigned int*)(xdst + (size_t)b * K0P + htid), val);
        }
    }
}

// ================= the persistent kernel =================
__global__ __launch_bounds__(256, 1) void lstm_all_k(
    const u16* __restrict__ w0, const u16* __restrict__ w1, const u16* __restrict__ w2,
    u16* A00, u16* A01, u16* A10, u16* A11, u16* A20, u16* A21,
    const u16* __restrict__ fcw, const float* __restrict__ bsum,
    const float* __restrict__ cells, const float* __restrict__ fcb,
    float* __restrict__ out, int* bar)
{
    __shared__ __align__(16) char smem[98304];

    const int tid  = threadIdx.x;
    const int lane = tid & 63;
    const int wid  = tid >> 6;
    const int wn   = (wid & 1) * 64;
    const int l15  = lane & 15;

    // XCD swizzle: 8 m-blocks sharing a W-panel land on one XCD
    const int id    = blockIdx.x;
    const int panel = (id & 7) * 4 + (id >> 6);   // 0..31  (j-panel)
    const int mblk  = (id >> 3) & 7;              // 0..7
    const int bm    = mblk * 64;
    const int j0    = panel * 32;

    // per-layer bias (this thread's 4 nf columns)
    v4f bv0, bv1, bv2;
    #pragma unroll
    for (int nf = 0; nf < 4; ++nf) {
        const int ncol = wn + nf * 16 + l15;
        const int idx  = (ncol >> 5) * H_DIM + j0 + (ncol & 31);
        bv0[nf] = bsum[idx];
        bv1[nf] = bsum[GATES + idx];
        bv2[nf] = bsum[2 * GATES + idx];
    }

    // persistent c-state in registers: this thread owns c[layer][gb][j0+jj..+7]
    const int erow = tid >> 2;
    const int jj   = (tid & 3) * 8;
    const int gb   = bm + erow;
    v4f c0a, c0b, c1a, c1b, c2a, c2b;
    {
        const float* cr = cells + (size_t)gb * H_DIM + j0 + jj;
        c0a = *(const v4f*)cr; c0b = *(const v4f*)(cr + 4);
        cr += (size_t)BATCH * H_DIM;
        c1a = *(const v4f*)cr; c1b = *(const v4f*)(cr + 4);
        cr += (size_t)BATCH * H_DIM;
        c2a = *(const v4f*)cr; c2b = *(const v4f*)(cr + 4);
    }

    int g = 0;
    #pragma unroll 1
    for (int t = 0; t < T_STEPS; ++t) {
        const int pr = t & 1;
        u16* A0r = pr ? A01 : A00;  u16* A0w = pr ? A00 : A01;
        u16* A1r = pr ? A11 : A10;  u16* A1w = pr ? A10 : A11;
        u16* A2r = pr ? A21 : A20;  u16* A2w = pr ? A20 : A21;

        // layer 0: reads [x(t)|h0(t-1)]; h0 -> own next-parity slot + layer1 x
        gemm_stage(smem, A0r, w0, K0P, K0P / 64, bv0, c0a, c0b,
                   A0w + IN_DIM, K0P, A1r, K12, bm, j0);
        grid_sync(bar, ++g);
        // layer 1
        gemm_stage(smem, A1r, w1, K12, K12 / 64, bv1, c1a, c1b,
                   A1w + H_DIM, K12, A2r, K12, bm, j0);
        grid_sync(bar, ++g);
        // layer 2
        gemm_stage(smem, A2r, w2, K12, K12 / 64, bv2, c2a, c2b,
                   A2w + H_DIM, K12, (u16*)nullptr, 0, bm, j0);
        grid_sync(bar, ++g);
        // FC: reads h2(t) (parity pn), writes out[:,t,:] and x(t+1)
        fc_stage(smem, A2w + H_DIM, K12, fcw, fcb, out, A0w, t, id);
        grid_sync(bar, ++g);
    }
}

// ================= prologue =================
__global__ __launch_bounds__(256) void convpack_k(
    const float* __restrict__ src, int srcStride,
    u16* __restrict__ dst, int dstStride, int cols8, long total8)
{
    long i = (long)blockIdx.x * 256 + threadIdx.x;
    if (i >= total8) return;
    const int r  = (int)(i / cols8);
    const int cc = (int)(i - (long)r * cols8) * 8;
    const float* s = src + (size_t)r * srcStride + cc;
    v4f a = *(const v4f*)s;
    v4f b = *(const v4f*)(s + 4);
    v8u16 o;
    #pragma unroll
    for (int q = 0; q < 4; ++q) { o[q] = f2bf(a[q]); o[4 + q] = f2bf(b[q]); }
    *(v8u16*)(dst + (size_t)r * dstStride + cc) = o;
}

__global__ __launch_bounds__(256) void zero16_k(
    u16* __restrict__ dst, int dstStride, int cols8, long total8)
{
    long i = (long)blockIdx.x * 256 + threadIdx.x;
    if (i >= total8) return;
    const int r  = (int)(i / cols8);
    const int cc = (int)(i - (long)r * cols8) * 8;
    v8u16 z = {0, 0, 0, 0, 0, 0, 0, 0};
    *(v8u16*)(dst + (size_t)r * dstStride + cc) = z;
}

__global__ __launch_bounds__(256) void add_k(
    const float* __restrict__ a, const float* __restrict__ b,
    float* __restrict__ o, int n)
{
    int i = blockIdx.x * 256 + threadIdx.x;
    if (i < n) o[i] = a[i] + b[i];
}

extern "C" void kernel_launch(void* const* d_in, const int* in_sizes, int n_in,
                              void* d_out, int out_size, void* d_ws, size_t ws_size,
                              hipStream_t stream)
{
    const float* inputs  = (const float*)d_in[0];
    const float* hiddens = (const float*)d_in[1];
    const float* cells   = (const float*)d_in[2];
    const float* Wih[3]  = {(const float*)d_in[3], (const float*)d_in[7],  (const float*)d_in[11]};
    const float* Whh[3]  = {(const float*)d_in[4], (const float*)d_in[8],  (const float*)d_in[12]};
    const float* bih[3]  = {(const float*)d_in[5], (const float*)d_in[9],  (const float*)d_in[13]};
    const float* bhh[3]  = {(const float*)d_in[6], (const float*)d_in[10], (const float*)d_in[14]};
    const float* fc_w    = (const float*)d_in[15];
    const float* fc_b    = (const float*)d_in[16];
    float* out = (float*)d_out;

    // ---- workspace carve-up ----
    char* p = (char*)d_ws;
    auto take = [&](size_t bytes) -> void* {
        void* r = p; p += (bytes + 255) & ~(size_t)255; return r;
    };
    const int Kl[3]  = {K0P, K12, K12};
    const int Kin[3] = {IN_DIM, H_DIM, H_DIM};
    u16* wcat[3];
    for (int l = 0; l < 3; ++l) wcat[l] = (u16*)take((size_t)GATES * Kl[l] * 2);
    u16* Ab[3][2];
    for (int l = 0; l < 3; ++l)
        for (int q = 0; q < 2; ++q) Ab[l][q] = (u16*)take((size_t)BATCH * Kl[l] * 2);
    u16*   fcwb = (u16*)take((size_t)IN_DIM * H_DIM * 2);
    float* bsum = (float*)take((size_t)3 * GATES * 4);
    int*   bar  = (int*)take(8192);
    if ((size_t)(p - (char*)d_ws) > ws_size) return;

    auto pack = [&](const float* s, int ss, u16* d, int ds, int rows, int cols) {
        long t8 = (long)rows * (cols / 8);
        convpack_k<<<(int)((t8 + 255) / 256), 256, 0, stream>>>(s, ss, d, ds, cols / 8, t8);
    };
    auto zero = [&](u16* d, int ds, int rows, int cols) {
        long t8 = (long)rows * (cols / 8);
        zero16_k<<<(int)((t8 + 255) / 256), 256, 0, stream>>>(d, ds, cols / 8, t8);
    };

    // weights -> bf16 concatenated [Wih | Whh | pad]
    for (int l = 0; l < 3; ++l) {
        pack(Wih[l], Kin[l], wcat[l],           Kl[l], GATES, Kin[l]);
        pack(Whh[l], H_DIM,  wcat[l] + Kin[l],  Kl[l], GATES, H_DIM);
    }
    zero(wcat[0] + IN_DIM + H_DIM, K0P, GATES, K0P - IN_DIM - H_DIM);
    pack(fc_w, H_DIM, fcwb, H_DIM, IN_DIM, H_DIM);

    // initial states (parity 0), x0, pads (both parities of layer0)
    for (int l = 0; l < 3; ++l)
        pack(hiddens + (size_t)l * BATCH * H_DIM, H_DIM,
             Ab[l][0] + Kin[l], Kl[l], BATCH, H_DIM);
    pack(inputs, T_STEPS * IN_DIM, Ab[0][0], K0P, BATCH, IN_DIM);   // x_0
    zero(Ab[0][0] + IN_DIM + H_DIM, K0P, BATCH, K0P - IN_DIM - H_DIM);
    zero(Ab[0][1] + IN_DIM + H_DIM, K0P, BATCH, K0P - IN_DIM - H_DIM);

    for (int l = 0; l < 3; ++l)
        add_k<<<16, 256, 0, stream>>>(bih[l], bhh[l], bsum + l * GATES, GATES);
    hipMemsetAsync(bar, 0, 8192, stream);

    // ---- the whole recurrence: one persistent kernel, plain launch ----
    lstm_all_k<<<NBLK, 256, 0, stream>>>(
        wcat[0], wcat[1], wcat[2],
        Ab[0][0], Ab[0][1], Ab[1][0], Ab[1][1], Ab[2][0], Ab[2][1],
        fcwb, bsum, cells, fc_b, out,
        bar);
}

// Round 8
// 4481.815 us; speedup vs baseline: 1.6271x; 1.2896x over previous
//
#include <hip/hip_runtime.h>
#include <cstdint>
#include <cstddef>

// Autoregressive 3-layer LSTM, B=512, T=75, IN=96, H=1024, bf16 MFMA compute.
// R8: 512-THREAD BLOCKS (8 waves = 2 waves/SIMD) on the R7 skeleton.
//   R7 post-mortem: barriers fixed (~2-3us) but K-loop runs ~1700cyc/iter vs
//   ~200cyc compute -> memory-stall-bound at 1 wave/SIMD (zero TLP: a vmcnt
//   stall idles the whole SIMD). Fix: same 64x128 tile, same 256-block grid,
//   8 waves/block -> each SIMD holds 2 waves that interleave; per-thread
//   staging drops to 3 gload/tile (depth-3 = vmcnt 9/6/3/0).
//   Memory scheme unchanged (R5/R7 proven): fence-free two-level barrier,
//   sc0|sc1-bypass A reads, write-through agent-atomic h/x writes, cached W.
//   c-state in registers; bias preloaded once.

typedef unsigned short u16;
typedef float v4f __attribute__((ext_vector_type(4)));
typedef short v8s __attribute__((ext_vector_type(8)));    // 8 bf16 (4 VGPRs)
typedef u16   v8u16 __attribute__((ext_vector_type(8)));

#define BATCH 512
#define H_DIM 1024
#define GATES 4096
#define T_STEPS 75
#define IN_DIM 96
#define K0P 1152              // layer0 K padded: 96 + 1024 + 32 zeros
#define K12 2048              // layers 1,2 K: 1024 + 1024
#define NBLK 256

__device__ __forceinline__ float bf2f(u16 u) {
    unsigned int x = ((unsigned int)u) << 16;
    return __builtin_bit_cast(float, x);
}
__device__ __forceinline__ u16 f2bf(float f) {   // round-to-nearest-even
    unsigned int x = __builtin_bit_cast(unsigned int, f);
    x += 0x7fffu + ((x >> 16) & 1u);
    return (u16)(x >> 16);
}
// cached load (weights: read-only; streamed via L2/L3)
__device__ __forceinline__ void gload16(const void* g, void* l) {
    __builtin_amdgcn_global_load_lds(
        (const __attribute__((address_space(1))) void*)g,
        (__attribute__((address_space(3))) void*)l, 16, 0, 0);
}
// coherent load (activations written by other blocks since last sync):
// aux = sc0|sc1 = 0x11 -> bypass stale L1/L2, read from coherence point
__device__ __forceinline__ void gload16c(const void* g, void* l) {
    __builtin_amdgcn_global_load_lds(
        (const __attribute__((address_space(1))) void*)g,
        (__attribute__((address_space(3))) void*)l, 16, 0, 0x11);
}
__device__ __forceinline__ void st_agent_u32(unsigned int* p, unsigned int v) {
    __hip_atomic_store(p, v, __ATOMIC_RELAXED, __HIP_MEMORY_SCOPE_AGENT);
}
__device__ __forceinline__ unsigned int ld_agent_u32(const unsigned int* p) {
    return __hip_atomic_load(p, __ATOMIC_RELAXED, __HIP_MEMORY_SCOPE_AGENT);
}

// ---- two-level grid barrier, contention-separated (R7, proven) ----
__device__ __forceinline__ void grid_sync(int* bar, int g) {
    __syncthreads();   // all waves: s_waitcnt vmcnt(0) -> stores visible
    if (threadIdx.x == 0) {
        int old = __hip_atomic_fetch_add(&bar[(blockIdx.x & 7) * 32], 1,
                                         __ATOMIC_RELAXED, __HIP_MEMORY_SCOPE_AGENT);
        if (old + 1 == 32 * g) {            // this block completed its group
            int r = __hip_atomic_fetch_add(&bar[256], 1,
                                           __ATOMIC_RELAXED, __HIP_MEMORY_SCOPE_AGENT);
            if (r + 1 == 8 * g)             // all groups complete
                __hip_atomic_store(&bar[288], g,
                                   __ATOMIC_RELAXED, __HIP_MEMORY_SCOPE_AGENT);
        }
        int spins = 0;
        while (__hip_atomic_load(&bar[288],
                                 __ATOMIC_RELAXED, __HIP_MEMORY_SCOPE_AGENT) < g) {
            if (++spins > (1 << 17)) break;   // watchdog: fail fast, not hang
            __builtin_amdgcn_s_sleep(1);
        }
    }
    __syncthreads();
}

// ---- fused gates-GEMM + LSTM cell stage ----
// block tile 64 rows x (4 gates x 32 j), 8 waves (4m x 2n), BK=64.
__device__ __forceinline__ void gemm_stage(
    char* smem, const u16* __restrict__ A, const u16* __restrict__ W,
    int K, int nk, v4f bv, v4f& cc,
    u16* __restrict__ h1, int h1s, u16* __restrict__ h2, int h2s,
    int bm, int j0)
{
    u16* sA = (u16*)smem;              // 4 bufs x 4096 u16 (64x64, 8KB each)
    u16* sB = (u16*)(smem + 32768);    // 4 bufs x 8192 u16 (128x64, 16KB each)

    const int tid  = threadIdx.x;
    const int lane = tid & 63;
    const int wid  = tid >> 6;          // 0..7
    const int wm   = (wid >> 1) * 16;   // wave m-offset: 0,16,32,48
    const int wn   = (wid & 1) * 64;    // wave n-offset: 0,64
    const int l15  = lane & 15;
    const int lq   = lane >> 4;         // 0..3

    v4f acc[4];
    #pragma unroll
    for (int nf = 0; nf < 4; ++nf) {
        v4f tv = {bv[nf], bv[nf], bv[nf], bv[nf]};
        acc[nf] = tv;
    }

    const int srow = tid >> 3;                                   // 0..63
    const int kcs  = ((tid & 7) ^ (srow & 7)) << 3;              // swizzled src k-elem

    auto stage = [&](int b, int k0) {
        u16* sa = sA + b * 4096;
        u16* sb = sB + b * 8192;
        // A: 64 rows x 64 k, one round (512 thr x 8 elem)
        gload16c(A + (size_t)(bm + srow) * K + k0 + kcs, sa + tid * 8);
        // W: 128 rows (gate-major) in two rounds
        #pragma unroll
        for (int q = 0; q < 2; ++q) {
            const int fr = q * 64 + srow;            // 0..127
            gload16(W + (size_t)((fr >> 5) * H_DIM + j0 + (fr & 31)) * K + k0 + kcs,
                    sb + q * 4096 + tid * 8);
        }
    };

    // depth-3 prologue (3 loads/thread/tile -> 9 outstanding)
    {
        const int npre = nk < 3 ? nk : 3;
        for (int p = 0; p < npre; ++p) stage(p, p * 64);
    }

    #pragma unroll 1
    for (int tt = 0; tt < nk; ++tt) {
        const int cur = tt & 3;
        if (tt + 3 < nk) stage((tt + 3) & 3, (tt + 3) * 64);
        const int ahead = (nk - 1 - tt) < 3 ? (nk - 1 - tt) : 3;
        if (ahead == 3)      asm volatile("s_waitcnt vmcnt(9)" ::: "memory");
        else if (ahead == 2) asm volatile("s_waitcnt vmcnt(6)" ::: "memory");
        else if (ahead == 1) asm volatile("s_waitcnt vmcnt(3)" ::: "memory");
        else                 asm volatile("s_waitcnt vmcnt(0)" ::: "memory");
        asm volatile("s_barrier" ::: "memory");

        const char* sa = (const char*)(sA + cur * 4096);
        const char* sb = (const char*)(sB + cur * 8192);
        v8s af[2], bfr[4][2];
        #pragma unroll
        for (int ks = 0; ks < 2; ++ks) {
            const int row = wm + l15;
            const int ch  = ks * 4 + lq;
            af[ks] = *(const v8s*)(sa + row * 128 + (((ch ^ (row & 7))) << 4));
        }
        #pragma unroll
        for (int nf = 0; nf < 4; ++nf)
            #pragma unroll
            for (int ks = 0; ks < 2; ++ks) {
                const int row = wn + nf * 16 + l15;
                const int ch  = ks * 4 + lq;
                bfr[nf][ks] = *(const v8s*)(sb + row * 128 + (((ch ^ (row & 7))) << 4));
            }
        #pragma unroll
        for (int ks = 0; ks < 2; ++ks)
            #pragma unroll
            for (int nf = 0; nf < 4; ++nf)
                acc[nf] = __builtin_amdgcn_mfma_f32_16x16x32_bf16(
                    af[ks], bfr[nf][ks], acc[nf], 0, 0, 0);
        asm volatile("s_barrier" ::: "memory");
    }

    // ---- epilogue: gates -> LDS, then cell (c in registers) ----
    float* sG = (float*)smem;   // [64][132] f32 = 33792B (reuses staging LDS)
    #pragma unroll
    for (int nf = 0; nf < 4; ++nf)
        #pragma unroll
        for (int r = 0; r < 4; ++r)
            sG[(wm + lq * 4 + r) * 132 + wn + nf * 16 + l15] = acc[nf][r];
    __syncthreads();

    const int erow = tid >> 3;           // 0..63
    const int jj   = (tid & 7) * 4;      // 0,4,..,28
    const int gb   = bm + erow;
    const float* sGr = sG + erow * 132;
    v4f n0;
    u16 hv[4];
    #pragma unroll
    for (int q = 0; q < 4; ++q) {
        const float gi = sGr[      jj + q];
        const float gf = sGr[32  + jj + q];
        const float gg = sGr[64  + jj + q];
        const float go = sGr[96  + jj + q];
        const float cv = cc[q];
        const float ii = 1.f / (1.f + __expf(-gi));
        const float ff = 1.f / (1.f + __expf(-gf));
        const float g2 = tanhf(gg);
        const float oo = 1.f / (1.f + __expf(-go));
        const float cq = ff * cv + ii * g2;
        n0[q] = cq;
        hv[q] = f2bf(oo * tanhf(cq));
    }
    cc = n0;
    // h writes: agent-scope atomic u32 stores (write-through; L2 never dirty)
    unsigned int* d1 = (unsigned int*)(h1 + (size_t)gb * h1s + j0 + jj);
    #pragma unroll
    for (int w2 = 0; w2 < 2; ++w2) {
        unsigned int val = (unsigned int)hv[2 * w2] | ((unsigned int)hv[2 * w2 + 1] << 16);
        st_agent_u32(d1 + w2, val);
    }
    if (h2) {
        unsigned int* d2 = (unsigned int*)(h2 + (size_t)gb * h2s + j0 + jj);
        #pragma unroll
        for (int w2 = 0; w2 < 2; ++w2) {
            unsigned int val = (unsigned int)hv[2 * w2] | ((unsigned int)hv[2 * w2 + 1] << 16);
            st_agent_u32(d2 + w2, val);
        }
    }
}

// ---- FC 1024->96 + hardtanh; 2 batch rows per block (512 threads) ----
__device__ __forceinline__ void fc_stage(
    char* smem, const u16* __restrict__ h2, int h2s,
    const u16* __restrict__ w, const float* __restrict__ fcb,
    float* __restrict__ out, u16* __restrict__ xdst, int t, int id)
{
    float* sh = (float*)smem;            // [2][1024] f32
    const int tid  = threadIdx.x;
    const int half = tid >> 8;           // 0,1
    const int htid = tid & 255;
    const int b    = id * 2 + half;      // 0..511
    // h2 was written cross-block since last sync -> coherent u32 loads (4 bf16/thr)
    const unsigned int* hp = (const unsigned int*)(h2 + (size_t)b * h2s + htid * 4);
    #pragma unroll
    for (int w4 = 0; w4 < 2; ++w4) {
        unsigned int u = ld_agent_u32(hp + w4);
        sh[half * H_DIM + htid * 4 + 2 * w4]     = bf2f((u16)(u & 0xffffu));
        sh[half * H_DIM + htid * 4 + 2 * w4 + 1] = bf2f((u16)(u >> 16));
    }
    __syncthreads();
    if (htid < IN_DIM) {
        const u16* wr = w + (size_t)htid * H_DIM;
        const float* shr = sh + half * H_DIM;
        float acc = fcb[htid];
        #pragma unroll 4
        for (int k = 0; k < H_DIM; k += 8) {
            v8u16 wv = *(const v8u16*)(wr + k);
            #pragma unroll
            for (int q = 0; q < 8; ++q) acc += shr[k + q] * bf2f(wv[q]);
        }
        acc = fminf(1.f, fmaxf(-1.f, acc));
        out[(size_t)b * (T_STEPS * IN_DIM) + t * IN_DIM + htid] = acc;
        // x write crosses the next sync: pair lanes -> one atomic u32 store
        float o2 = __shfl_xor(acc, 1);
        if ((htid & 1) == 0) {
            unsigned int val = (unsigned int)f2bf(acc) | ((unsigned int)f2bf(o2) << 16);
            st_agent_u32((unsigned int*)(xdst + (size_t)b * K0P + htid), val);
        }
    }
}

// ================= the persistent kernel =================
__global__ __launch_bounds__(512, 1) void lstm_all_k(
    const u16* __restrict__ w0, const u16* __restrict__ w1, const u16* __restrict__ w2,
    u16* A00, u16* A01, u16* A10, u16* A11, u16* A20, u16* A21,
    const u16* __restrict__ fcw, const float* __restrict__ bsum,
    const float* __restrict__ cells, const float* __restrict__ fcb,
    float* __restrict__ out, int* bar)
{
    __shared__ __align__(16) char smem[98304];

    const int tid  = threadIdx.x;
    const int lane = tid & 63;
    const int wid  = tid >> 6;
    const int wn   = (wid & 1) * 64;
    const int l15  = lane & 15;

    // XCD swizzle: 8 m-blocks sharing a W-panel land on one XCD
    const int id    = blockIdx.x;
    const int panel = (id & 7) * 4 + (id >> 6);   // 0..31  (j-panel)
    const int mblk  = (id >> 3) & 7;              // 0..7
    const int bm    = mblk * 64;
    const int j0    = panel * 32;

    // per-layer bias (this thread's 4 nf columns)
    v4f bv0, bv1, bv2;
    #pragma unroll
    for (int nf = 0; nf < 4; ++nf) {
        const int ncol = wn + nf * 16 + l15;
        const int idx  = (ncol >> 5) * H_DIM + j0 + (ncol & 31);
        bv0[nf] = bsum[idx];
        bv1[nf] = bsum[GATES + idx];
        bv2[nf] = bsum[2 * GATES + idx];
    }

    // persistent c-state in registers: this thread owns c[layer][gb][j0+jj..+3]
    const int erow = tid >> 3;
    const int jj   = (tid & 7) * 4;
    const int gb   = bm + erow;
    v4f c0, c1, c2;
    {
        const float* cr = cells + (size_t)gb * H_DIM + j0 + jj;
        c0 = *(const v4f*)cr;
        cr += (size_t)BATCH * H_DIM;
        c1 = *(const v4f*)cr;
        cr += (size_t)BATCH * H_DIM;
        c2 = *(const v4f*)cr;
    }

    int g = 0;
    #pragma unroll 1
    for (int t = 0; t < T_STEPS; ++t) {
        const int pr = t & 1;
        u16* A0r = pr ? A01 : A00;  u16* A0w = pr ? A00 : A01;
        u16* A1r = pr ? A11 : A10;  u16* A1w = pr ? A10 : A11;
        u16* A2r = pr ? A21 : A20;  u16* A2w = pr ? A20 : A21;

        // layer 0: reads [x(t)|h0(t-1)]; h0 -> own next-parity slot + layer1 x
        gemm_stage(smem, A0r, w0, K0P, K0P / 64, bv0, c0,
                   A0w + IN_DIM, K0P, A1r, K12, bm, j0);
        grid_sync(bar, ++g);
        // layer 1
        gemm_stage(smem, A1r, w1, K12, K12 / 64, bv1, c1,
                   A1w + H_DIM, K12, A2r, K12, bm, j0);
        grid_sync(bar, ++g);
        // layer 2
        gemm_stage(smem, A2r, w2, K12, K12 / 64, bv2, c2,
                   A2w + H_DIM, K12, (u16*)nullptr, 0, bm, j0);
        grid_sync(bar, ++g);
        // FC: reads h2(t) (parity pn), writes out[:,t,:] and x(t+1)
        fc_stage(smem, A2w + H_DIM, K12, fcw, fcb, out, A0w, t, id);
        grid_sync(bar, ++g);
    }
}

// ================= prologue =================
__global__ __launch_bounds__(256) void convpack_k(
    const float* __restrict__ src, int srcStride,
    u16* __restrict__ dst, int dstStride, int cols8, long total8)
{
    long i = (long)blockIdx.x * 256 + threadIdx.x;
    if (i >= total8) return;
    const int r  = (int)(i / cols8);
    const int cc = (int)(i - (long)r * cols8) * 8;
    const float* s = src + (size_t)r * srcStride + cc;
    v4f a = *(const v4f*)s;
    v4f b = *(const v4f*)(s + 4);
    v8u16 o;
    #pragma unroll
    for (int q = 0; q < 4; ++q) { o[q] = f2bf(a[q]); o[4 + q] = f2bf(b[q]); }
    *(v8u16*)(dst + (size_t)r * dstStride + cc) = o;
}

__global__ __launch_bounds__(256) void zero16_k(
    u16* __restrict__ dst, int dstStride, int cols8, long total8)
{
    long i = (long)blockIdx.x * 256 + threadIdx.x;
    if (i >= total8) return;
    const int r  = (int)(i / cols8);
    const int cc = (int)(i - (long)r * cols8) * 8;
    v8u16 z = {0, 0, 0, 0, 0, 0, 0, 0};
    *(v8u16*)(dst + (size_t)r * dstStride + cc) = z;
}

__global__ __launch_bounds__(256) void add_k(
    const float* __restrict__ a, const float* __restrict__ b,
    float* __restrict__ o, int n)
{
    int i = blockIdx.x * 256 + threadIdx.x;
    if (i < n) o[i] = a[i] + b[i];
}

extern "C" void kernel_launch(void* const* d_in, const int* in_sizes, int n_in,
                              void* d_out, int out_size, void* d_ws, size_t ws_size,
                              hipStream_t stream)
{
    const float* inputs  = (const float*)d_in[0];
    const float* hiddens = (const float*)d_in[1];
    const float* cells   = (const float*)d_in[2];
    const float* Wih[3]  = {(const float*)d_in[3], (const float*)d_in[7],  (const float*)d_in[11]};
    const float* Whh[3]  = {(const float*)d_in[4], (const float*)d_in[8],  (const float*)d_in[12]};
    const float* bih[3]  = {(const float*)d_in[5], (const float*)d_in[9],  (const float*)d_in[13]};
    const float* bhh[3]  = {(const float*)d_in[6], (const float*)d_in[10], (const float*)d_in[14]};
    const float* fc_w    = (const float*)d_in[15];
    const float* fc_b    = (const float*)d_in[16];
    float* out = (float*)d_out;

    // ---- workspace carve-up ----
    char* p = (char*)d_ws;
    auto take = [&](size_t bytes) -> void* {
        void* r = p; p += (bytes + 255) & ~(size_t)255; return r;
    };
    const int Kl[3]  = {K0P, K12, K12};
    const int Kin[3] = {IN_DIM, H_DIM, H_DIM};
    u16* wcat[3];
    for (int l = 0; l < 3; ++l) wcat[l] = (u16*)take((size_t)GATES * Kl[l] * 2);
    u16* Ab[3][2];
    for (int l = 0; l < 3; ++l)
        for (int q = 0; q < 2; ++q) Ab[l][q] = (u16*)take((size_t)BATCH * Kl[l] * 2);
    u16*   fcwb = (u16*)take((size_t)IN_DIM * H_DIM * 2);
    float* bsum = (float*)take((size_t)3 * GATES * 4);
    int*   bar  = (int*)take(8192);
    if ((size_t)(p - (char*)d_ws) > ws_size) return;

    auto pack = [&](const float* s, int ss, u16* d, int ds, int rows, int cols) {
        long t8 = (long)rows * (cols / 8);
        convpack_k<<<(int)((t8 + 255) / 256), 256, 0, stream>>>(s, ss, d, ds, cols / 8, t8);
    };
    auto zero = [&](u16* d, int ds, int rows, int cols) {
        long t8 = (long)rows * (cols / 8);
        zero16_k<<<(int)((t8 + 255) / 256), 256, 0, stream>>>(d, ds, cols / 8, t8);
    };

    // weights -> bf16 concatenated [Wih | Whh | pad]
    for (int l = 0; l < 3; ++l) {
        pack(Wih[l], Kin[l], wcat[l],           Kl[l], GATES, Kin[l]);
        pack(Whh[l], H_DIM,  wcat[l] + Kin[l],  Kl[l], GATES, H_DIM);
    }
    zero(wcat[0] + IN_DIM + H_DIM, K0P, GATES, K0P - IN_DIM - H_DIM);
    pack(fc_w, H_DIM, fcwb, H_DIM, IN_DIM, H_DIM);

    // initial states (parity 0), x0, pads (both parities of layer0)
    for (int l = 0; l < 3; ++l)
        pack(hiddens + (size_t)l * BATCH * H_DIM, H_DIM,
             Ab[l][0] + Kin[l], Kl[l], BATCH, H_DIM);
    pack(inputs, T_STEPS * IN_DIM, Ab[0][0], K0P, BATCH, IN_DIM);   // x_0
    zero(Ab[0][0] + IN_DIM + H_DIM, K0P, BATCH, K0P - IN_DIM - H_DIM);
    zero(Ab[0][1] + IN_DIM + H_DIM, K0P, BATCH, K0P - IN_DIM - H_DIM);

    for (int l = 0; l < 3; ++l)
        add_k<<<16, 256, 0, stream>>>(bih[l], bhh[l], bsum + l * GATES, GATES);
    hipMemsetAsync(bar, 0, 8192, stream);

    // ---- the whole recurrence: one persistent kernel, plain launch ----
    lstm_all_k<<<NBLK, 512, 0, stream>>>(
        wcat[0], wcat[1], wcat[2],
        Ab[0][0], Ab[0][1], Ab[1][0], Ab[1][1], Ab[2][0], Ab[2][1],
        fcwb, bsum, cells, fc_b, out,
        bar);
}